// Round 8
// baseline (138.635 us; speedup 1.0000x reference)
//
#include <hip/hip_runtime.h>
#include <math.h>

typedef float f4 __attribute__((ext_vector_type(4)));

constexpr int N_ELEM = 4096;
constexpr int NCHUNK = 16;          // 16 chunks x 256 elems (64 lanes x float4)
constexpr int ROWS_PER_BLOCK = 4;   // one wave per row
constexpr int PF = 6;               // rolling prefetch window (dwordx4 in flight)
constexpr float LOG2E = 1.4426950408889634f;
constexpr float LN2   = 0.6931471805599453f;

// One WAVE per row; lane l, chunk c owns float4 at 256c + 4l (lane-contiguous,
// fully coalesced). Neighbor exchange via in-wave shuffles + deferred lane-63
// coefficient. Math in log2 domain; ln2 folded into the final scale:
//   m = -|x|*log2e, L2 = log2(1+2^m)
//   log2 p = min(x,0)*log2e - L2 ; p = 2^(log2 p) ; log2 p + log2(1-p) = m - 2*L2
// __launch_bounds__(256,8): VGPR<=64 so all 8 blocks/CU co-resident
// (2048 blocks = 256 CU x 8 -> single dispatch round).
// PF=6: 6 KB of loads in flight per wave (R6->R7 showed in-flight depth was
// still sub-saturating; this is the remaining supported lever).
__global__ __launch_bounds__(256, 8) void row_loss_kernel(
        const float* __restrict__ in,
        const float* __restrict__ tgt,
        float* __restrict__ partials,
        float invN) {
    const int t = threadIdx.x;
    const int w = t >> 6;
    const int l = t & 63;
    const int row_idx = blockIdx.x * ROWS_PER_BLOCK + w;
    const float* __restrict__ row = in + (size_t)row_idx * N_ELEM + (l << 2);

    const float tb = tgt[row_idx];   // wave-uniform -> scalar load

    f4 buf[PF];                      // statically indexed after unroll -> VGPRs
#pragma unroll
    for (int c = 0; c < PF; ++c)
        buf[c] = *reinterpret_cast<const f4*>(row + (c << 8));

    float accH = 0.0f;   // sum p*(p_left+p_right)*log2(p)
    float accL = 0.0f;   // sum log2 p + log2(1-p)
    float prev_p3 = 0.0f;
    float dc = 0.0f;     // lane-63 deferred coefficient p3*lp3

#pragma unroll
    for (int c = 0; c < NCHUNK; ++c) {
        f4 v = buf[c % PF];
        if (c + PF < NCHUNK)         // refill the slot just consumed
            buf[c % PF] = *reinterpret_cast<const f4*>(row + ((c + PF) << 8));

        float p[4], lp[4];
#pragma unroll
        for (int j = 0; j < 4; ++j) {
            float x   = v[j];
            float m   = -fabsf(x) * LOG2E;              // log2 e^{-|x|}
            float e2  = __builtin_amdgcn_exp2f(m);      // e^{-|x|}
            float L2  = __builtin_amdgcn_logf(1.0f + e2);  // log2(1+e^{-|x|})
            float lp2 = fmaf(fminf(x, 0.0f), LOG2E, -L2);  // log2 p
            p[j]  = __builtin_amdgcn_exp2f(lp2);        // sigmoid(x)
            lp[j] = lp2;
            accL += fmaf(-2.0f, L2, m);                 // log2 p + log2(1-p)
        }

        // Resolve prev chunk's lane-63 deferred right-neighbor term:
        // its right neighbor is this chunk's lane-0 p0.
        float b0 = __shfl(p[0], 0);
        accH += dc * b0;

        // In-wave neighbor exchange.
        float leftP  = __shfl_up(p[3], 1);       // lane l-1's p3 = p[idx-1]
        float rightP = __shfl_down(p[0], 1);     // lane l+1's p0 = p[idx+4]
        float p3b    = __shfl(prev_p3, 63);      // prev chunk lane-63's p3
        if (l == 0)  leftP  = (c == 0) ? 0.0f : p3b;   // row start pads 0
        if (l == 63) rightP = 0.0f;                     // deferred via dc

        accH += p[0] * (leftP + p[1])  * lp[0];
        accH += p[1] * (p[0]  + p[2])  * lp[1];
        accH += p[2] * (p[1]  + p[3])  * lp[2];
        accH += p[3] * (p[2]  + rightP)* lp[3];

        dc = (l == 63) ? p[3] * lp[3] : 0.0f;
        prev_p3 = p[3];
    }
    // Row end: last chunk lane-63 right neighbor is 0 -> dc term drops.

    float total = (-tb * LN2) * (accH + invN * accL);

    // In-wave reduce, then one tiny LDS combine -> per-BLOCK partial.
#pragma unroll
    for (int off = 32; off; off >>= 1) total += __shfl_down(total, off);

    __shared__ float sm[4];
    if (l == 0) sm[w] = total;
    __syncthreads();
    if (t == 0) partials[blockIdx.x] = (sm[0] + sm[1]) + (sm[2] + sm[3]);
}

// Mean over block partials (nblk = 2048) -> scalar.
__global__ __launch_bounds__(256) void reduce_mean_kernel(
        const float* __restrict__ part, float* __restrict__ out,
        int nblk, float invB) {
    const int nvec = nblk >> 2;
    float acc = 0.0f;
    for (int i = threadIdx.x; i < nvec; i += 256) {
        f4 v = reinterpret_cast<const f4*>(part)[i];
        acc += (v.x + v.y) + (v.z + v.w);
    }
#pragma unroll
    for (int off = 32; off; off >>= 1) acc += __shfl_down(acc, off);
    __shared__ float sm[4];
    if ((threadIdx.x & 63) == 0) sm[threadIdx.x >> 6] = acc;
    __syncthreads();
    if (threadIdx.x == 0) out[0] = ((sm[0] + sm[1]) + (sm[2] + sm[3])) * invB;
}

extern "C" void kernel_launch(void* const* d_in, const int* in_sizes, int n_in,
                              void* d_out, int out_size, void* d_ws, size_t ws_size,
                              hipStream_t stream) {
    const float* inputs  = (const float*)d_in[0];
    const float* targets = (const float*)d_in[1];
    float* out = (float*)d_out;

    const int B = in_sizes[1];                 // 8192 rows
    const int nblk = B / ROWS_PER_BLOCK;       // 2048 blocks

    float* partials = (float*)d_ws;            // nblk floats of scratch

    row_loss_kernel<<<nblk, 256, 0, stream>>>(
        inputs, targets, partials, 1.0f / (float)N_ELEM);
    reduce_mean_kernel<<<1, 256, 0, stream>>>(
        partials, out, nblk, 1.0f / (float)B);
}

// Round 9
// 29.585 us; speedup vs baseline: 4.6860x; 4.6860x over previous
//
#include <hip/hip_runtime.h>
#include <math.h>

typedef float f4 __attribute__((ext_vector_type(4)));

constexpr int N_ELEM = 4096;
constexpr int NCHUNK = 16;          // 16 chunks x 256 elems (64 lanes x float4)
constexpr int ROWS_PER_BLOCK = 4;   // one wave per row
constexpr int PF = 4;               // rolling prefetch window (dwordx4 in flight)
                                    // PF=6 spills (R8: 272MB scratch writes) — 4 is the VGPR-budget max
constexpr float LOG2E = 1.4426950408889634f;
constexpr float LN2   = 0.6931471805599453f;

// One WAVE per row; lane l, chunk c owns float4 at 256c + 4l (lane-contiguous,
// fully coalesced). Neighbor exchange via in-wave shuffles + deferred lane-63
// coefficient. Math in log2 domain; ln2 folded into the final scale:
//   m = -|x|*log2e, L2 = log2(1+2^m)
//   log2 p = min(x,0)*log2e - L2 ; p = 2^(log2 p) ; log2 p + log2(1-p) = m - 2*L2
// __launch_bounds__(256,8): VGPR<=64 so all 8 blocks/CU are co-resident
// (2048 blocks = 256 CU x 8 -> single dispatch round).
__global__ __launch_bounds__(256, 8) void row_loss_kernel(
        const float* __restrict__ in,
        const float* __restrict__ tgt,
        float* __restrict__ partials,
        float invN) {
    const int t = threadIdx.x;
    const int w = t >> 6;
    const int l = t & 63;
    const int row_idx = blockIdx.x * ROWS_PER_BLOCK + w;
    const float* __restrict__ row = in + (size_t)row_idx * N_ELEM + (l << 2);

    const float tb = tgt[row_idx];   // wave-uniform -> scalar load

    f4 buf[PF];                      // statically indexed after unroll -> VGPRs
#pragma unroll
    for (int c = 0; c < PF; ++c)
        buf[c] = *reinterpret_cast<const f4*>(row + (c << 8));

    float accH = 0.0f;   // sum p*(p_left+p_right)*log2(p)
    float accL = 0.0f;   // sum log2 p + log2(1-p)
    float prev_p3 = 0.0f;
    float dc = 0.0f;     // lane-63 deferred coefficient p3*lp3

#pragma unroll
    for (int c = 0; c < NCHUNK; ++c) {
        f4 v = buf[c & (PF - 1)];
        if (c + PF < NCHUNK)         // refill the slot just consumed
            buf[c & (PF - 1)] = *reinterpret_cast<const f4*>(row + ((c + PF) << 8));

        float p[4], lp[4];
#pragma unroll
        for (int j = 0; j < 4; ++j) {
            float x   = v[j];
            float m   = -fabsf(x) * LOG2E;              // log2 e^{-|x|}
            float e2  = __builtin_amdgcn_exp2f(m);      // e^{-|x|}
            float L2  = __builtin_amdgcn_logf(1.0f + e2);  // log2(1+e^{-|x|})
            float lp2 = fmaf(fminf(x, 0.0f), LOG2E, -L2);  // log2 p
            p[j]  = __builtin_amdgcn_exp2f(lp2);        // sigmoid(x)
            lp[j] = lp2;
            accL += fmaf(-2.0f, L2, m);                 // log2 p + log2(1-p)
        }

        // Resolve prev chunk's lane-63 deferred right-neighbor term:
        // its right neighbor is this chunk's lane-0 p0.
        float b0 = __shfl(p[0], 0);
        accH += dc * b0;

        // In-wave neighbor exchange.
        float leftP  = __shfl_up(p[3], 1);       // lane l-1's p3 = p[idx-1]
        float rightP = __shfl_down(p[0], 1);     // lane l+1's p0 = p[idx+4]
        float p3b    = __shfl(prev_p3, 63);      // prev chunk lane-63's p3
        if (l == 0)  leftP  = (c == 0) ? 0.0f : p3b;   // row start pads 0
        if (l == 63) rightP = 0.0f;                     // deferred via dc

        accH += p[0] * (leftP + p[1])  * lp[0];
        accH += p[1] * (p[0]  + p[2])  * lp[1];
        accH += p[2] * (p[1]  + p[3])  * lp[2];
        accH += p[3] * (p[2]  + rightP)* lp[3];

        dc = (l == 63) ? p[3] * lp[3] : 0.0f;
        prev_p3 = p[3];
    }
    // Row end: last chunk lane-63 right neighbor is 0 -> dc term drops.

    float total = (-tb * LN2) * (accH + invN * accL);

    // In-wave reduce, then one tiny LDS combine -> per-BLOCK partial.
#pragma unroll
    for (int off = 32; off; off >>= 1) total += __shfl_down(total, off);

    __shared__ float sm[4];
    if (l == 0) sm[w] = total;
    __syncthreads();
    if (t == 0) partials[blockIdx.x] = (sm[0] + sm[1]) + (sm[2] + sm[3]);
}

// Mean over block partials (nblk = 2048) -> scalar.
__global__ __launch_bounds__(256) void reduce_mean_kernel(
        const float* __restrict__ part, float* __restrict__ out,
        int nblk, float invB) {
    const int nvec = nblk >> 2;
    float acc = 0.0f;
    for (int i = threadIdx.x; i < nvec; i += 256) {
        f4 v = reinterpret_cast<const f4*>(part)[i];
        acc += (v.x + v.y) + (v.z + v.w);
    }
#pragma unroll
    for (int off = 32; off; off >>= 1) acc += __shfl_down(acc, off);
    __shared__ float sm[4];
    if ((threadIdx.x & 63) == 0) sm[threadIdx.x >> 6] = acc;
    __syncthreads();
    if (threadIdx.x == 0) out[0] = ((sm[0] + sm[1]) + (sm[2] + sm[3])) * invB;
}

extern "C" void kernel_launch(void* const* d_in, const int* in_sizes, int n_in,
                              void* d_out, int out_size, void* d_ws, size_t ws_size,
                              hipStream_t stream) {
    const float* inputs  = (const float*)d_in[0];
    const float* targets = (const float*)d_in[1];
    float* out = (float*)d_out;

    const int B = in_sizes[1];                 // 8192 rows
    const int nblk = B / ROWS_PER_BLOCK;       // 2048 blocks

    float* partials = (float*)d_ws;            // nblk floats of scratch

    row_loss_kernel<<<nblk, 256, 0, stream>>>(
        inputs, targets, partials, 1.0f / (float)N_ELEM);
    reduce_mean_kernel<<<1, 256, 0, stream>>>(
        partials, out, nblk, 1.0f / (float)B);
}